// Round 2
// baseline (3517.827 us; speedup 1.0000x reference)
//
#include <hip/hip_runtime.h>

typedef _Float16 half8 __attribute__((ext_vector_type(8)));
typedef _Float16 half4 __attribute__((ext_vector_type(4)));
typedef float floatx4 __attribute__((ext_vector_type(4)));
typedef unsigned long long u64;

#define T_STEPS 512
#define IN_DIM 256
#define HID 512
#define RING 8

__device__ inline float sig_f(float x) { return 1.f / (1.f + __expf(-x)); }
__device__ inline float tanh_f(float x) {
  float t = __expf(-2.f * fabsf(x));
  return copysignf((1.f - t) / (1.f + t), x);
}

// ---- LLC-coherent (agent-scope) scalar accessors — proven in R3 ----
__device__ inline void cstore_pair(_Float16* p, float a, float b) {
  union { unsigned u; _Float16 h[2]; } pk;
  pk.h[0] = (_Float16)a; pk.h[1] = (_Float16)b;
  __hip_atomic_store((unsigned*)p, pk.u, __ATOMIC_RELAXED, __HIP_MEMORY_SCOPE_AGENT);
}
__device__ inline unsigned poll_llc(const unsigned* p) {
  return __hip_atomic_load(p, __ATOMIC_RELAXED, __HIP_MEMORY_SCOPE_AGENT);
}
__device__ inline u64 cload64(const _Float16* p) {
  return __hip_atomic_load((const u64*)p, __ATOMIC_RELAXED, __HIP_MEMORY_SCOPE_AGENT);
}
__device__ inline half8 cload_h8(const _Float16* p) {
  union { u64 u[2]; half8 v; } r;
  r.u[0] = cload64(p);
  r.u[1] = cload64(p + 4);
  return r.v;
}

// 16x16B coherent loads from one base, 64B stride (one full 512-col row half
// per lane-group). Issued back-to-back so all 16 share ~one LLC round trip.
#define LD16_BODY                                              \
  "global_load_dwordx4 %0, %16, off sc0 sc1\n\t"               \
  "global_load_dwordx4 %1, %16, off offset:64 sc0 sc1\n\t"     \
  "global_load_dwordx4 %2, %16, off offset:128 sc0 sc1\n\t"    \
  "global_load_dwordx4 %3, %16, off offset:192 sc0 sc1\n\t"    \
  "global_load_dwordx4 %4, %16, off offset:256 sc0 sc1\n\t"    \
  "global_load_dwordx4 %5, %16, off offset:320 sc0 sc1\n\t"    \
  "global_load_dwordx4 %6, %16, off offset:384 sc0 sc1\n\t"    \
  "global_load_dwordx4 %7, %16, off offset:448 sc0 sc1\n\t"    \
  "global_load_dwordx4 %8, %16, off offset:512 sc0 sc1\n\t"    \
  "global_load_dwordx4 %9, %16, off offset:576 sc0 sc1\n\t"    \
  "global_load_dwordx4 %10, %16, off offset:640 sc0 sc1\n\t"   \
  "global_load_dwordx4 %11, %16, off offset:704 sc0 sc1\n\t"   \
  "global_load_dwordx4 %12, %16, off offset:768 sc0 sc1\n\t"   \
  "global_load_dwordx4 %13, %16, off offset:832 sc0 sc1\n\t"   \
  "global_load_dwordx4 %14, %16, off offset:896 sc0 sc1\n\t"   \
  "global_load_dwordx4 %15, %16, off offset:960 sc0 sc1"

// Safe variant: waitcnt inside the asm block, consumers depend on asm outputs.
__device__ inline void ld16_llc(const _Float16* base, half8 (&r)[16]) {
  floatx4 t0, t1, t2, t3, t4, t5, t6, t7, t8, t9, t10, t11, t12, t13, t14, t15;
  asm volatile(LD16_BODY "\n\t"
               "s_waitcnt vmcnt(0)"
               : "=&v"(t0), "=&v"(t1), "=&v"(t2), "=&v"(t3),
                 "=&v"(t4), "=&v"(t5), "=&v"(t6), "=&v"(t7),
                 "=&v"(t8), "=&v"(t9), "=&v"(t10), "=&v"(t11),
                 "=&v"(t12), "=&v"(t13), "=&v"(t14), "=&v"(t15)
               : "v"(base)
               : "memory");
  r[0] = __builtin_bit_cast(half8, t0);   r[1] = __builtin_bit_cast(half8, t1);
  r[2] = __builtin_bit_cast(half8, t2);   r[3] = __builtin_bit_cast(half8, t3);
  r[4] = __builtin_bit_cast(half8, t4);   r[5] = __builtin_bit_cast(half8, t5);
  r[6] = __builtin_bit_cast(half8, t6);   r[7] = __builtin_bit_cast(half8, t7);
  r[8] = __builtin_bit_cast(half8, t8);   r[9] = __builtin_bit_cast(half8, t9);
  r[10] = __builtin_bit_cast(half8, t10); r[11] = __builtin_bit_cast(half8, t11);
  r[12] = __builtin_bit_cast(half8, t12); r[13] = __builtin_bit_cast(half8, t13);
  r[14] = __builtin_bit_cast(half8, t14); r[15] = __builtin_bit_cast(half8, t15);
}

// Wave-parallel wait on 64 flags (call from one full wave; others at barrier).
__device__ inline void waitf(const unsigned* fg, unsigned tg) {
  if (tg == 0) return;
  const unsigned* p = fg + (threadIdx.x & 63) * 32;
  int it = 0;
  while (!__all((int)(poll_llc(p) >= tg))) {
    if (++it > 4) __builtin_amdgcn_s_sleep(1);
  }
}

__device__ inline floatx4 mfma16(half8 a, half8 b, floatx4 c) {
  return __builtin_amdgcn_mfma_f32_16x16x32_f16(a, b, c, 0, 0, 0);
}

__global__ void init_kernel(const float* __restrict__ x, const float* __restrict__ hc,
                            _Float16* __restrict__ x16, _Float16* __restrict__ h0b,
                            _Float16* __restrict__ h1b, unsigned* __restrict__ flagbase) {
  size_t i = (size_t)blockIdx.x * blockDim.x + threadIdx.x;
  size_t stride = (size_t)gridDim.x * blockDim.x;
  const size_t n4 = (size_t)T_STEPS * 64 * IN_DIM / 4;
  const floatx4* xv = (const floatx4*)x;
  for (size_t idx = i; idx < n4; idx += stride) {
    floatx4 v = xv[idx];
    half4 h;
    h.x = (_Float16)v.x; h.y = (_Float16)v.y;
    h.z = (_Float16)v.z; h.w = (_Float16)v.w;
    *(half4*)(x16 + idx * 4) = h;
  }
  if (i < 16384) {
    // h0[-1] -> ring slot 7; h1[-1] -> parity 1 (LLC-coherent stores).
    cstore_pair(h0b + (size_t)(RING - 1) * 32768 + 2 * i, hc[2 * i], hc[2 * i + 1]);
    cstore_pair(h1b + 32768 + 2 * i, hc[32768 + 2 * i], hc[32768 + 2 * i + 1]);
  }
  if (i < 4096) {  // zero both flag arrays (2 x 8192 B contiguous)
    __hip_atomic_store(flagbase + i, 0u, __ATOMIC_RELAXED, __HIP_MEMORY_SCOPE_AGENT);
  }
}

// R6 (= R5 de-risked): blocks 0..63 = L0, 64..127 = L1; per-layer flags,
// 8-deep h0 ring, LLC coherence only. Changes vs measured R4 baseline:
//  - L0 h-load: one 16-load batch (1 RTT instead of 2).
//  - L1: both waits merged into one wave-parallel round; ALL 32 h0+h1 loads
//    issued back-to-back in two asm blocks, then a SINGLE vmcnt(0) drain
//    (no counted vmcnt -> robust to any compiler-inserted memory op), then
//    sched_barrier(0) so no MFMA consumer is hoisted above the drain.
//    4 serialized RTTs + 2 wait rounds -> ~1 RTT + 1 wait round.
__global__ __launch_bounds__(256, 1) void lstm_kernel(
    const _Float16* __restrict__ x16, _Float16* __restrict__ h0b, _Float16* __restrict__ h1b,
    unsigned* __restrict__ flags0, unsigned* __restrict__ flags1,
    const float* __restrict__ W_ih0, const float* __restrict__ W_hh0,
    const float* __restrict__ b_ih0, const float* __restrict__ b_hh0,
    const float* __restrict__ W_ih1, const float* __restrict__ W_hh1,
    const float* __restrict__ b_ih1, const float* __restrict__ b_hh1,
    const float* __restrict__ W_out, const float* __restrict__ b_out,
    const float* __restrict__ hc, float* __restrict__ out) {
  __shared__ __align__(16) _Float16 wlds[32 * 1032];
  __shared__ float cbuf[64 * 36];
  __shared__ float cstate[512];
  __shared__ float blds[32];

  const int bq = blockIdx.x;
  const bool isL0 = bq < 64;
  const int q = isL0 ? bq : bq - 64;
  const int col0 = q * 8;
  const int Ka = isL0 ? IN_DIM : HID;
  const int K = Ka + HID;
  const int WP = K + 8;
  const float* Wa = isL0 ? W_ih0 : W_ih1;
  const float* Wb = isL0 ? W_hh0 : W_hh1;
  const float* bia = isL0 ? b_ih0 : b_ih1;
  const float* bib = isL0 ? b_hh0 : b_hh1;
  unsigned* myflag = (isL0 ? flags0 : flags1) + q * 32;

  for (int idx = threadIdx.x; idx < 32 * K; idx += 256) {
    int r = idx / K;
    int k = idx - r * K;
    int g = r >> 3, j = r & 7;
    int grow = g * HID + col0 + j;  // PyTorch gate order i,f,g,o
    float w = (k < Ka) ? Wa[(size_t)grow * Ka + k] : Wb[(size_t)grow * HID + (k - Ka)];
    wlds[r * WP + k] = (_Float16)w;
  }
  if (threadIdx.x < 32) {
    int g = threadIdx.x >> 3, j = threadIdx.x & 7;
    int grow = g * HID + col0 + j;
    blds[threadIdx.x] = bia[grow] + bib[grow];
  }
  {
    int layer = isL0 ? 0 : 1;
    for (int idx = threadIdx.x; idx < 512; idx += 256) {
      int m = idx >> 3, j = idx & 7;
      cstate[idx] = hc[(size_t)(2 + layer) * 32768 + m * HID + col0 + j];
    }
  }
  __syncthreads();

  const int lane = threadIdx.x & 63;
  const int wv = threadIdx.x >> 6;   // 0..3
  const int lrow = lane & 15;
  const int kq = (lane >> 4) * 8;
  const int m0 = wv * 16;
  const _Float16* wrow0 = wlds + lrow * WP;
  const _Float16* wrow1 = wlds + (16 + lrow) * WP;

  // Recurrent-half B fragments in registers/AGPRs (proven in R2/R3).
  half8 breg0[16], breg1[16];
#pragma unroll
  for (int c = 0; c < 16; ++c) {
    breg0[c] = *(const half8*)(wrow0 + Ka + c * 32 + kq);
    breg1[c] = *(const half8*)(wrow1 + Ka + c * 32 + kq);
  }

  const int gm = threadIdx.x >> 2;
  const int gj = (threadIdx.x & 3) * 2;

  for (int t = 0; t < T_STEPS; ++t) {
    floatx4 acc0 = {0.f, 0.f, 0.f, 0.f};
    floatx4 acc1 = {0.f, 0.f, 0.f, 0.f};
    _Float16* dst;

    if (isL0) {
      // X phase (no cross-block dep): compute before the wait.
      const _Float16* a0p = x16 + (size_t)t * (64 * IN_DIM) + (m0 + lrow) * IN_DIM + kq;
#pragma unroll
      for (int c = 0; c < 8; ++c) {
        half8 a = *(const half8*)(a0p + c * 32);
        half8 b0v = *(const half8*)(wrow0 + c * 32 + kq);
        half8 b1v = *(const half8*)(wrow1 + c * 32 + kq);
        acc0 = mfma16(a, b0v, acc0);
        acc1 = mfma16(a, b1v, acc1);
      }
      // Merged wait: wave0 -> peers' h0[t-1]; wave1 -> ring slot free.
      if (threadIdx.x < 64) waitf(flags0, (unsigned)t);
      else if (threadIdx.x < 128) waitf(flags1, (t >= RING) ? (unsigned)(t - RING + 1) : 0u);
      __syncthreads();
      asm volatile("" ::: "memory");
      const _Float16* a1p = h0b + (size_t)((t - 1) & (RING - 1)) * 32768 + (m0 + lrow) * HID + kq;
      half8 av[16];
      ld16_llc(a1p, av);  // one RTT for the full recurrent row
#pragma unroll
      for (int c = 0; c < 16; ++c) {
        acc0 = mfma16(av[c], breg0[c], acc0);
        acc1 = mfma16(av[c], breg1[c], acc1);
      }
      dst = h0b + (size_t)(t & (RING - 1)) * 32768;
    } else {
      // Merged wait: wave0 -> h0[t] ready; wave1 -> peers' h1[t-1].
      if (threadIdx.x < 64) waitf(flags0, (unsigned)(t + 1));
      else if (threadIdx.x < 128) waitf(flags1, (unsigned)t);
      __syncthreads();
      asm volatile("" ::: "memory");
      const _Float16* a0p = h0b + (size_t)(t & (RING - 1)) * 32768 + (m0 + lrow) * HID + kq;
      const _Float16* a1p = h1b + (size_t)((t - 1) & 1) * 32768 + (m0 + lrow) * HID + kq;
      // Issue ALL 32 loads back-to-back, then ONE drain; one shared RTT.
      floatx4 p0, p1, p2, p3, p4, p5, p6, p7, p8, p9, p10, p11, p12, p13, p14, p15;
      floatx4 q0, q1, q2, q3, q4, q5, q6, q7, q8, q9, q10, q11, q12, q13, q14, q15;
      asm volatile(LD16_BODY
                   : "=&v"(p0), "=&v"(p1), "=&v"(p2), "=&v"(p3),
                     "=&v"(p4), "=&v"(p5), "=&v"(p6), "=&v"(p7),
                     "=&v"(p8), "=&v"(p9), "=&v"(p10), "=&v"(p11),
                     "=&v"(p12), "=&v"(p13), "=&v"(p14), "=&v"(p15)
                   : "v"(a0p)
                   : "memory");
      asm volatile(LD16_BODY
                   : "=&v"(q0), "=&v"(q1), "=&v"(q2), "=&v"(q3),
                     "=&v"(q4), "=&v"(q5), "=&v"(q6), "=&v"(q7),
                     "=&v"(q8), "=&v"(q9), "=&v"(q10), "=&v"(q11),
                     "=&v"(q12), "=&v"(q13), "=&v"(q14), "=&v"(q15)
                   : "v"(a1p)
                   : "memory");
      asm volatile("s_waitcnt vmcnt(0)" ::: "memory");  // single drain, all 32
      __builtin_amdgcn_sched_barrier(0);  // no consumer hoists above the drain
#define PH1(c, P)                                                          \
  {                                                                        \
    half8 aa = __builtin_bit_cast(half8, P);                               \
    acc0 = mfma16(aa, *(const half8*)(wrow0 + (c) * 32 + kq), acc0);       \
    acc1 = mfma16(aa, *(const half8*)(wrow1 + (c) * 32 + kq), acc1);       \
  }
      PH1(0, p0) PH1(1, p1) PH1(2, p2) PH1(3, p3)
      PH1(4, p4) PH1(5, p5) PH1(6, p6) PH1(7, p7)
      PH1(8, p8) PH1(9, p9) PH1(10, p10) PH1(11, p11)
      PH1(12, p12) PH1(13, p13) PH1(14, p14) PH1(15, p15)
#undef PH1
#define PH2(c, Q)                                                          \
  {                                                                        \
    half8 aa = __builtin_bit_cast(half8, Q);                               \
    acc0 = mfma16(aa, breg0[c], acc0);                                     \
    acc1 = mfma16(aa, breg1[c], acc1);                                     \
  }
      PH2(0, q0) PH2(1, q1) PH2(2, q2) PH2(3, q3)
      PH2(4, q4) PH2(5, q5) PH2(6, q6) PH2(7, q7)
      PH2(8, q8) PH2(9, q9) PH2(10, q10) PH2(11, q11)
      PH2(12, q12) PH2(13, q13) PH2(14, q14) PH2(15, q15)
#undef PH2
      dst = h1b + (size_t)(t & 1) * 32768;
    }

    // C/D layout: col = lane&15 (gate row), row = (lane>>4)*4 + reg (batch)
    const int mrow = m0 + (lane >> 4) * 4;
#pragma unroll
    for (int r2 = 0; r2 < 4; ++r2) {
      cbuf[(mrow + r2) * 36 + lrow] = acc0[r2];
      cbuf[(mrow + r2) * 36 + 16 + lrow] = acc1[r2];
    }
    __syncthreads();

    float hv[2];
#pragma unroll
    for (int e = 0; e < 2; ++e) {
      int j = gj + e;
      float xi = cbuf[gm * 36 + j] + blds[j];
      float xf = cbuf[gm * 36 + 8 + j] + blds[8 + j];
      float xg = cbuf[gm * 36 + 16 + j] + blds[16 + j];
      float xo = cbuf[gm * 36 + 24 + j] + blds[24 + j];
      float ig = sig_f(xi), fg = sig_f(xf), gg = tanh_f(xg), og = sig_f(xo);
      float c = fg * cstate[gm * 8 + j] + ig * gg;
      cstate[gm * 8 + j] = c;
      hv[e] = og * tanh_f(c);
    }
    cstore_pair(dst + gm * HID + col0 + gj, hv[0], hv[1]);

    // Release: drain stores, join block, one flag store.
    asm volatile("s_waitcnt vmcnt(0)" ::: "memory");
    __syncthreads();
    if (threadIdx.x == 0) {
      __hip_atomic_store(myflag, (unsigned)(t + 1), __ATOMIC_RELAXED, __HIP_MEMORY_SCOPE_AGENT);
    }
    asm volatile("" ::: "memory");
  }

  // Final linear on L0 blocks: out[64,256] = h1[511] @ W_out^T + b_out.
  if (isL0) {
    if (threadIdx.x < 64) waitf(flags1, (unsigned)T_STEPS);
    __syncthreads();
    asm volatile("" ::: "memory");
    const int oc = q * 4 + (threadIdx.x & 3);
    const int m = threadIdx.x >> 2;
    const _Float16* hrow = h1b + 32768 + m * HID;  // h1[511] at parity 1
    const float* wrow = W_out + (size_t)oc * HID;
    float sum = 0.f;
#pragma unroll 4
    for (int h = 0; h < HID; h += 8) {
      half8 hvv = cload_h8(hrow + h);
#pragma unroll
      for (int e = 0; e < 8; ++e) sum += (float)hvv[e] * wrow[h + e];
    }
    out[m * 256 + oc] = sum + b_out[oc];
  }
}

extern "C" void kernel_launch(void* const* d_in, const int* in_sizes, int n_in,
                              void* d_out, int out_size, void* d_ws, size_t ws_size,
                              hipStream_t stream) {
  const float* x     = (const float*)d_in[0];
  const float* hc    = (const float*)d_in[1];
  const float* W_ih0 = (const float*)d_in[2];
  const float* W_hh0 = (const float*)d_in[3];
  const float* b_ih0 = (const float*)d_in[4];
  const float* b_hh0 = (const float*)d_in[5];
  const float* W_ih1 = (const float*)d_in[6];
  const float* W_hh1 = (const float*)d_in[7];
  const float* b_ih1 = (const float*)d_in[8];
  const float* b_hh1 = (const float*)d_in[9];
  const float* W_out = (const float*)d_in[10];
  const float* b_out = (const float*)d_in[11];
  float* out = (float*)d_out;

  char* ws = (char*)d_ws;
  _Float16* x16 = (_Float16*)ws;                              // 16 MB
  _Float16* h0b = (_Float16*)(ws + 16777216);                 // 8 x 64 KB ring
  _Float16* h1b = (_Float16*)(ws + 16777216 + 8 * 65536);     // 2 x 64 KB
  unsigned* flags0 = (unsigned*)(ws + 16777216 + 10 * 65536);           // 64 x 128 B
  unsigned* flags1 = (unsigned*)(ws + 16777216 + 10 * 65536 + 8192);    // 64 x 128 B

  init_kernel<<<2048, 256, 0, stream>>>(x, hc, x16, h0b, h1b, flags0);
  lstm_kernel<<<128, 256, 0, stream>>>(x16, h0b, h1b, flags0, flags1,
                                       W_ih0, W_hh0, b_ih0, b_hh0,
                                       W_ih1, W_hh1, b_ih1, b_hh1,
                                       W_out, b_out, hc, out);
}

// Round 3
// 3225.694 us; speedup vs baseline: 1.0906x; 1.0906x over previous
//
#include <hip/hip_runtime.h>

typedef _Float16 half8 __attribute__((ext_vector_type(8)));
typedef _Float16 half4 __attribute__((ext_vector_type(4)));
typedef float floatx4 __attribute__((ext_vector_type(4)));
typedef unsigned long long u64;

#define T_STEPS 512
#define IN_DIM 256
#define HID 512
#define RING 8

__device__ inline float sig_f(float x) { return 1.f / (1.f + __expf(-x)); }
__device__ inline float tanh_f(float x) {
  float t = __expf(-2.f * fabsf(x));
  return copysignf((1.f - t) / (1.f + t), x);
}

// ---- LLC-coherent (agent-scope) scalar accessors — proven in R3 ----
__device__ inline void cstore_pair(_Float16* p, float a, float b) {
  union { unsigned u; _Float16 h[2]; } pk;
  pk.h[0] = (_Float16)a; pk.h[1] = (_Float16)b;
  __hip_atomic_store((unsigned*)p, pk.u, __ATOMIC_RELAXED, __HIP_MEMORY_SCOPE_AGENT);
}
__device__ inline unsigned poll_llc(const unsigned* p) {
  return __hip_atomic_load(p, __ATOMIC_RELAXED, __HIP_MEMORY_SCOPE_AGENT);
}
__device__ inline u64 cload64(const _Float16* p) {
  return __hip_atomic_load((const u64*)p, __ATOMIC_RELAXED, __HIP_MEMORY_SCOPE_AGENT);
}
__device__ inline half8 cload_h8(const _Float16* p) {
  union { u64 u[2]; half8 v; } r;
  r.u[0] = cload64(p);
  r.u[1] = cload64(p + 4);
  return r.v;
}

// 16x16B coherent loads from one base, 64B stride (a full 512-col row half per
// lane-group) issued back-to-back with ONE waitcnt -> ~1 pipelined LLC RTT.
// waitcnt stays inside the asm block; consumers depend on the asm outputs, so
// no counted-vmcnt fragility and no hoisting hazard.
#define LD16_BODY                                              \
  "global_load_dwordx4 %0, %16, off sc0 sc1\n\t"               \
  "global_load_dwordx4 %1, %16, off offset:64 sc0 sc1\n\t"     \
  "global_load_dwordx4 %2, %16, off offset:128 sc0 sc1\n\t"    \
  "global_load_dwordx4 %3, %16, off offset:192 sc0 sc1\n\t"    \
  "global_load_dwordx4 %4, %16, off offset:256 sc0 sc1\n\t"    \
  "global_load_dwordx4 %5, %16, off offset:320 sc0 sc1\n\t"    \
  "global_load_dwordx4 %6, %16, off offset:384 sc0 sc1\n\t"    \
  "global_load_dwordx4 %7, %16, off offset:448 sc0 sc1\n\t"    \
  "global_load_dwordx4 %8, %16, off offset:512 sc0 sc1\n\t"    \
  "global_load_dwordx4 %9, %16, off offset:576 sc0 sc1\n\t"    \
  "global_load_dwordx4 %10, %16, off offset:640 sc0 sc1\n\t"   \
  "global_load_dwordx4 %11, %16, off offset:704 sc0 sc1\n\t"   \
  "global_load_dwordx4 %12, %16, off offset:768 sc0 sc1\n\t"   \
  "global_load_dwordx4 %13, %16, off offset:832 sc0 sc1\n\t"   \
  "global_load_dwordx4 %14, %16, off offset:896 sc0 sc1\n\t"   \
  "global_load_dwordx4 %15, %16, off offset:960 sc0 sc1"

__device__ inline void ld16_llc(const _Float16* base, half8 (&r)[16]) {
  floatx4 t0, t1, t2, t3, t4, t5, t6, t7, t8, t9, t10, t11, t12, t13, t14, t15;
  asm volatile(LD16_BODY "\n\t"
               "s_waitcnt vmcnt(0)"
               : "=&v"(t0), "=&v"(t1), "=&v"(t2), "=&v"(t3),
                 "=&v"(t4), "=&v"(t5), "=&v"(t6), "=&v"(t7),
                 "=&v"(t8), "=&v"(t9), "=&v"(t10), "=&v"(t11),
                 "=&v"(t12), "=&v"(t13), "=&v"(t14), "=&v"(t15)
               : "v"(base)
               : "memory");
  r[0] = __builtin_bit_cast(half8, t0);   r[1] = __builtin_bit_cast(half8, t1);
  r[2] = __builtin_bit_cast(half8, t2);   r[3] = __builtin_bit_cast(half8, t3);
  r[4] = __builtin_bit_cast(half8, t4);   r[5] = __builtin_bit_cast(half8, t5);
  r[6] = __builtin_bit_cast(half8, t6);   r[7] = __builtin_bit_cast(half8, t7);
  r[8] = __builtin_bit_cast(half8, t8);   r[9] = __builtin_bit_cast(half8, t9);
  r[10] = __builtin_bit_cast(half8, t10); r[11] = __builtin_bit_cast(half8, t11);
  r[12] = __builtin_bit_cast(half8, t12); r[13] = __builtin_bit_cast(half8, t13);
  r[14] = __builtin_bit_cast(half8, t14); r[15] = __builtin_bit_cast(half8, t15);
}

// Wave-parallel wait on 64 flags (call from one full wave; others at barrier).
__device__ inline void waitf(const unsigned* fg, unsigned tg) {
  if (tg == 0) return;
  const unsigned* p = fg + (threadIdx.x & 63) * 32;
  int it = 0;
  while (!__all((int)(poll_llc(p) >= tg))) {
    if (++it > 4) __builtin_amdgcn_s_sleep(1);
  }
}

__device__ inline floatx4 mfma16(half8 a, half8 b, floatx4 c) {
  return __builtin_amdgcn_mfma_f32_16x16x32_f16(a, b, c, 0, 0, 0);
}

__global__ void init_kernel(const float* __restrict__ x, const float* __restrict__ hc,
                            _Float16* __restrict__ x16, _Float16* __restrict__ h0b,
                            _Float16* __restrict__ h1b, unsigned* __restrict__ flagbase) {
  size_t i = (size_t)blockIdx.x * blockDim.x + threadIdx.x;
  size_t stride = (size_t)gridDim.x * blockDim.x;
  const size_t n4 = (size_t)T_STEPS * 64 * IN_DIM / 4;
  const floatx4* xv = (const floatx4*)x;
  for (size_t idx = i; idx < n4; idx += stride) {
    floatx4 v = xv[idx];
    half4 h;
    h.x = (_Float16)v.x; h.y = (_Float16)v.y;
    h.z = (_Float16)v.z; h.w = (_Float16)v.w;
    *(half4*)(x16 + idx * 4) = h;
  }
  if (i < 16384) {
    // h0[-1] -> ring slot 7; h1[-1] -> parity 1 (LLC-coherent stores).
    cstore_pair(h0b + (size_t)(RING - 1) * 32768 + 2 * i, hc[2 * i], hc[2 * i + 1]);
    cstore_pair(h1b + 32768 + 2 * i, hc[32768 + 2 * i], hc[32768 + 2 * i + 1]);
  }
  if (i < 4096) {  // zero both flag arrays (2 x 8192 B contiguous)
    __hip_atomic_store(flagbase + i, 0u, __ATOMIC_RELAXED, __HIP_MEMORY_SCOPE_AGENT);
  }
}

// R7 = R4's PROVEN schedule (wait placement untouched — L1's flags1 wait stays
// AFTER the h0 phase so peer-flag visibility hides under real work; R6 exposing
// it at step-top cost 14%) with ONLY the loads merged: each pair of ld8_llc
// (2 serialized RTTs, vmcnt(0) each) becomes one ld16_llc (1 RTT).
__global__ __launch_bounds__(256, 1) void lstm_kernel(
    const _Float16* __restrict__ x16, _Float16* __restrict__ h0b, _Float16* __restrict__ h1b,
    unsigned* __restrict__ flags0, unsigned* __restrict__ flags1,
    const float* __restrict__ W_ih0, const float* __restrict__ W_hh0,
    const float* __restrict__ b_ih0, const float* __restrict__ b_hh0,
    const float* __restrict__ W_ih1, const float* __restrict__ W_hh1,
    const float* __restrict__ b_ih1, const float* __restrict__ b_hh1,
    const float* __restrict__ W_out, const float* __restrict__ b_out,
    const float* __restrict__ hc, float* __restrict__ out) {
  __shared__ __align__(16) _Float16 wlds[32 * 1032];
  __shared__ float cbuf[64 * 36];
  __shared__ float cstate[512];
  __shared__ float blds[32];

  const int bq = blockIdx.x;
  const bool isL0 = bq < 64;
  const int q = isL0 ? bq : bq - 64;
  const int col0 = q * 8;
  const int Ka = isL0 ? IN_DIM : HID;
  const int K = Ka + HID;
  const int WP = K + 8;
  const float* Wa = isL0 ? W_ih0 : W_ih1;
  const float* Wb = isL0 ? W_hh0 : W_hh1;
  const float* bia = isL0 ? b_ih0 : b_ih1;
  const float* bib = isL0 ? b_hh0 : b_hh1;
  unsigned* myflag = (isL0 ? flags0 : flags1) + q * 32;

  for (int idx = threadIdx.x; idx < 32 * K; idx += 256) {
    int r = idx / K;
    int k = idx - r * K;
    int g = r >> 3, j = r & 7;
    int grow = g * HID + col0 + j;  // PyTorch gate order i,f,g,o
    float w = (k < Ka) ? Wa[(size_t)grow * Ka + k] : Wb[(size_t)grow * HID + (k - Ka)];
    wlds[r * WP + k] = (_Float16)w;
  }
  if (threadIdx.x < 32) {
    int g = threadIdx.x >> 3, j = threadIdx.x & 7;
    int grow = g * HID + col0 + j;
    blds[threadIdx.x] = bia[grow] + bib[grow];
  }
  {
    int layer = isL0 ? 0 : 1;
    for (int idx = threadIdx.x; idx < 512; idx += 256) {
      int m = idx >> 3, j = idx & 7;
      cstate[idx] = hc[(size_t)(2 + layer) * 32768 + m * HID + col0 + j];
    }
  }
  __syncthreads();

  const int lane = threadIdx.x & 63;
  const int wv = threadIdx.x >> 6;   // 0..3
  const int lrow = lane & 15;
  const int kq = (lane >> 4) * 8;
  const int m0 = wv * 16;
  const _Float16* wrow0 = wlds + lrow * WP;
  const _Float16* wrow1 = wlds + (16 + lrow) * WP;

  // Recurrent-half B fragments in registers/AGPRs (proven in R2/R3).
  half8 breg0[16], breg1[16];
#pragma unroll
  for (int c = 0; c < 16; ++c) {
    breg0[c] = *(const half8*)(wrow0 + Ka + c * 32 + kq);
    breg1[c] = *(const half8*)(wrow1 + Ka + c * 32 + kq);
  }

  const int gm = threadIdx.x >> 2;
  const int gj = (threadIdx.x & 3) * 2;

  for (int t = 0; t < T_STEPS; ++t) {
    floatx4 acc0 = {0.f, 0.f, 0.f, 0.f};
    floatx4 acc1 = {0.f, 0.f, 0.f, 0.f};
    _Float16* dst;
    half8 av[16];

    if (isL0) {
      // X phase (no cross-block dep): compute before the wait.
      const _Float16* a0p = x16 + (size_t)t * (64 * IN_DIM) + (m0 + lrow) * IN_DIM + kq;
#pragma unroll
      for (int c = 0; c < 8; ++c) {
        half8 a = *(const half8*)(a0p + c * 32);
        half8 b0v = *(const half8*)(wrow0 + c * 32 + kq);
        half8 b1v = *(const half8*)(wrow1 + c * 32 + kq);
        acc0 = mfma16(a, b0v, acc0);
        acc1 = mfma16(a, b1v, acc1);
      }
      // Merged wait: wave0 -> peers' h0[t-1]; wave1 -> ring slot free.
      if (threadIdx.x < 64) waitf(flags0, (unsigned)t);
      else if (threadIdx.x < 128) waitf(flags1, (t >= RING) ? (unsigned)(t - RING + 1) : 0u);
      __syncthreads();
      asm volatile("" ::: "memory");
      const _Float16* a1p = h0b + (size_t)((t - 1) & (RING - 1)) * 32768 + (m0 + lrow) * HID + kq;
      ld16_llc(a1p, av);  // one RTT for the full recurrent row (was 2)
#pragma unroll
      for (int c = 0; c < 16; ++c) {
        acc0 = mfma16(av[c], breg0[c], acc0);
        acc1 = mfma16(av[c], breg1[c], acc1);
      }
      dst = h0b + (size_t)(t & (RING - 1)) * 32768;
    } else {
      if (threadIdx.x < 64) waitf(flags0, (unsigned)(t + 1));  // h0[t] ready (L0 runs ahead: ~free)
      __syncthreads();
      asm volatile("" ::: "memory");
      const _Float16* a0p = h0b + (size_t)(t & (RING - 1)) * 32768 + (m0 + lrow) * HID + kq;
      ld16_llc(a0p, av);  // one RTT (was 2)
#pragma unroll
      for (int c = 0; c < 16; ++c) {
        half8 b0v = *(const half8*)(wrow0 + c * 32 + kq);
        half8 b1v = *(const half8*)(wrow1 + c * 32 + kq);
        acc0 = mfma16(av[c], b0v, acc0);
        acc1 = mfma16(av[c], b1v, acc1);
      }
      // flags1 wait AFTER the h0 phase: peer-flag visibility hides under the
      // load+MFMA work above (R4-proven placement; hoisting it cost 14% in R6).
      if (threadIdx.x < 64) waitf(flags1, (unsigned)t);  // peers' h1[t-1]
      __syncthreads();
      asm volatile("" ::: "memory");
      const _Float16* a1p = h1b + (size_t)((t - 1) & 1) * 32768 + (m0 + lrow) * HID + kq;
      ld16_llc(a1p, av);  // one RTT (was 2)
#pragma unroll
      for (int c = 0; c < 16; ++c) {
        acc0 = mfma16(av[c], breg0[c], acc0);
        acc1 = mfma16(av[c], breg1[c], acc1);
      }
      dst = h1b + (size_t)(t & 1) * 32768;
    }

    // C/D layout: col = lane&15 (gate row), row = (lane>>4)*4 + reg (batch)
    const int mrow = m0 + (lane >> 4) * 4;
#pragma unroll
    for (int r2 = 0; r2 < 4; ++r2) {
      cbuf[(mrow + r2) * 36 + lrow] = acc0[r2];
      cbuf[(mrow + r2) * 36 + 16 + lrow] = acc1[r2];
    }
    __syncthreads();

    float hv[2];
#pragma unroll
    for (int e = 0; e < 2; ++e) {
      int j = gj + e;
      float xi = cbuf[gm * 36 + j] + blds[j];
      float xf = cbuf[gm * 36 + 8 + j] + blds[8 + j];
      float xg = cbuf[gm * 36 + 16 + j] + blds[16 + j];
      float xo = cbuf[gm * 36 + 24 + j] + blds[24 + j];
      float ig = sig_f(xi), fg = sig_f(xf), gg = tanh_f(xg), og = sig_f(xo);
      float c = fg * cstate[gm * 8 + j] + ig * gg;
      cstate[gm * 8 + j] = c;
      hv[e] = og * tanh_f(c);
    }
    cstore_pair(dst + gm * HID + col0 + gj, hv[0], hv[1]);

    // Release: drain stores, join block, one flag store.
    asm volatile("s_waitcnt vmcnt(0)" ::: "memory");
    __syncthreads();
    if (threadIdx.x == 0) {
      __hip_atomic_store(myflag, (unsigned)(t + 1), __ATOMIC_RELAXED, __HIP_MEMORY_SCOPE_AGENT);
    }
    asm volatile("" ::: "memory");
  }

  // Final linear on L0 blocks: out[64,256] = h1[511] @ W_out^T + b_out.
  if (isL0) {
    if (threadIdx.x < 64) waitf(flags1, (unsigned)T_STEPS);
    __syncthreads();
    asm volatile("" ::: "memory");
    const int oc = q * 4 + (threadIdx.x & 3);
    const int m = threadIdx.x >> 2;
    const _Float16* hrow = h1b + 32768 + m * HID;  // h1[511] at parity 1
    const float* wrow = W_out + (size_t)oc * HID;
    float sum = 0.f;
#pragma unroll 4
    for (int h = 0; h < HID; h += 8) {
      half8 hvv = cload_h8(hrow + h);
#pragma unroll
      for (int e = 0; e < 8; ++e) sum += (float)hvv[e] * wrow[h + e];
    }
    out[m * 256 + oc] = sum + b_out[oc];
  }
}

extern "C" void kernel_launch(void* const* d_in, const int* in_sizes, int n_in,
                              void* d_out, int out_size, void* d_ws, size_t ws_size,
                              hipStream_t stream) {
  const float* x     = (const float*)d_in[0];
  const float* hc    = (const float*)d_in[1];
  const float* W_ih0 = (const float*)d_in[2];
  const float* W_hh0 = (const float*)d_in[3];
  const float* b_ih0 = (const float*)d_in[4];
  const float* b_hh0 = (const float*)d_in[5];
  const float* W_ih1 = (const float*)d_in[6];
  const float* W_hh1 = (const float*)d_in[7];
  const float* b_ih1 = (const float*)d_in[8];
  const float* b_hh1 = (const float*)d_in[9];
  const float* W_out = (const float*)d_in[10];
  const float* b_out = (const float*)d_in[11];
  float* out = (float*)d_out;

  char* ws = (char*)d_ws;
  _Float16* x16 = (_Float16*)ws;                              // 16 MB
  _Float16* h0b = (_Float16*)(ws + 16777216);                 // 8 x 64 KB ring
  _Float16* h1b = (_Float16*)(ws + 16777216 + 8 * 65536);     // 2 x 64 KB
  unsigned* flags0 = (unsigned*)(ws + 16777216 + 10 * 65536);           // 64 x 128 B
  unsigned* flags1 = (unsigned*)(ws + 16777216 + 10 * 65536 + 8192);    // 64 x 128 B

  init_kernel<<<2048, 256, 0, stream>>>(x, hc, x16, h0b, h1b, flags0);
  lstm_kernel<<<128, 256, 0, stream>>>(x16, h0b, h1b, flags0, flags1,
                                       W_ih0, W_hh0, b_ih0, b_hh0,
                                       W_ih1, W_hh1, b_ih1, b_hh1,
                                       W_out, b_out, hc, out);
}

// Round 4
// 2979.537 us; speedup vs baseline: 1.1807x; 1.0826x over previous
//
#include <hip/hip_runtime.h>

typedef _Float16 half8 __attribute__((ext_vector_type(8)));
typedef _Float16 half4 __attribute__((ext_vector_type(4)));
typedef float floatx4 __attribute__((ext_vector_type(4)));
typedef unsigned uintx4 __attribute__((ext_vector_type(4)));
typedef unsigned long long u64;

#define T_STEPS 512
#define IN_DIM 256
#define HID 512
#define RING 8

__device__ inline float sig_f(float x) { return 1.f / (1.f + __expf(-x)); }
__device__ inline float tanh_f(float x) {
  float t = __expf(-2.f * fabsf(x));
  return copysignf((1.f - t) / (1.f + t), x);
}
__device__ inline unsigned umin_(unsigned a, unsigned b) { return a < b ? a : b; }

// ---- LLC-coherent (agent-scope) accessors — proven in R3/R4 ----
__device__ inline void cstore_pair(_Float16* p, float a, float b) {
  union { unsigned u; _Float16 h[2]; } pk;
  pk.h[0] = (_Float16)a; pk.h[1] = (_Float16)b;
  __hip_atomic_store((unsigned*)p, pk.u, __ATOMIC_RELAXED, __HIP_MEMORY_SCOPE_AGENT);
}
__device__ inline u64 cload64(const _Float16* p) {
  return __hip_atomic_load((const u64*)p, __ATOMIC_RELAXED, __HIP_MEMORY_SCOPE_AGENT);
}
__device__ inline half8 cload_h8(const _Float16* p) {
  union { u64 u[2]; half8 v; } r;
  r.u[0] = cload64(p);
  r.u[1] = cload64(p + 4);
  return r.v;
}

// 8x16B batched coherent loads, one waitcnt (R4-proven load path).
__device__ inline void ld8_llc(const _Float16* base, half8 (&r)[8]) {
  floatx4 t0, t1, t2, t3, t4, t5, t6, t7;
  asm volatile(
      "global_load_dwordx4 %0, %8, off sc0 sc1\n\t"
      "global_load_dwordx4 %1, %8, off offset:64 sc0 sc1\n\t"
      "global_load_dwordx4 %2, %8, off offset:128 sc0 sc1\n\t"
      "global_load_dwordx4 %3, %8, off offset:192 sc0 sc1\n\t"
      "global_load_dwordx4 %4, %8, off offset:256 sc0 sc1\n\t"
      "global_load_dwordx4 %5, %8, off offset:320 sc0 sc1\n\t"
      "global_load_dwordx4 %6, %8, off offset:384 sc0 sc1\n\t"
      "global_load_dwordx4 %7, %8, off offset:448 sc0 sc1\n\t"
      "s_waitcnt vmcnt(0)"
      : "=&v"(t0), "=&v"(t1), "=&v"(t2), "=&v"(t3),
        "=&v"(t4), "=&v"(t5), "=&v"(t6), "=&v"(t7)
      : "v"(base)
      : "memory");
  r[0] = __builtin_bit_cast(half8, t0); r[1] = __builtin_bit_cast(half8, t1);
  r[2] = __builtin_bit_cast(half8, t2); r[3] = __builtin_bit_cast(half8, t3);
  r[4] = __builtin_bit_cast(half8, t4); r[5] = __builtin_bit_cast(half8, t5);
  r[6] = __builtin_bit_cast(half8, t6); r[7] = __builtin_bit_cast(half8, t7);
}

// Wave-parallel wait: lane i checks block i's FOUR per-wave sub-flags with one
// 16B load (same 1-RTT poll as a scalar flag).
__device__ inline void waitf4(const unsigned* fg, unsigned tg) {
  if (tg == 0) return;
  const unsigned* p = fg + (threadIdx.x & 63) * 32;
  int it = 0;
  for (;;) {
    floatx4 t;
    asm volatile("global_load_dwordx4 %0, %1, off sc0 sc1\n\t"
                 "s_waitcnt vmcnt(0)"
                 : "=&v"(t) : "v"(p) : "memory");
    uintx4 u = __builtin_bit_cast(uintx4, t);
    unsigned m = umin_(umin_(u.x, u.y), umin_(u.z, u.w));
    if (__all((int)(m >= tg))) return;
    if (++it > 4) __builtin_amdgcn_s_sleep(1);
  }
}

// Poll fg1 until >= tg1 while ALSO sampling fg0 >= tg0 in the same pipelined
// round (both 16B loads share one RTT). Returns whether fg0 condition held on
// the final iteration -> caller may skip its NEXT exposed fg0 wait.
__device__ inline bool waitf4_dual(const unsigned* fg1, unsigned tg1,
                                   const unsigned* fg0, unsigned tg0) {
  const unsigned* p1 = fg1 + (threadIdx.x & 63) * 32;
  const unsigned* p0 = fg0 + (threadIdx.x & 63) * 32;
  unsigned m1, m0v;
  int it = 0;
  for (;;) {
    floatx4 t1, t0;
    asm volatile("global_load_dwordx4 %0, %2, off sc0 sc1\n\t"
                 "global_load_dwordx4 %1, %3, off sc0 sc1\n\t"
                 "s_waitcnt vmcnt(0)"
                 : "=&v"(t1), "=&v"(t0)
                 : "v"(p1), "v"(p0)
                 : "memory");
    uintx4 u1 = __builtin_bit_cast(uintx4, t1);
    uintx4 u0 = __builtin_bit_cast(uintx4, t0);
    m1 = umin_(umin_(u1.x, u1.y), umin_(u1.z, u1.w));
    m0v = umin_(umin_(u0.x, u0.y), umin_(u0.z, u0.w));
    if (__all((int)(m1 >= tg1))) break;
    if (++it > 4) __builtin_amdgcn_s_sleep(1);
  }
  return (bool)__all((int)(m0v >= tg0));
}

__device__ inline floatx4 mfma16(half8 a, half8 b, floatx4 c) {
  return __builtin_amdgcn_mfma_f32_16x16x32_f16(a, b, c, 0, 0, 0);
}

__global__ void init_kernel(const float* __restrict__ x, const float* __restrict__ hc,
                            _Float16* __restrict__ x16, _Float16* __restrict__ h0b,
                            _Float16* __restrict__ h1b, unsigned* __restrict__ flagbase) {
  size_t i = (size_t)blockIdx.x * blockDim.x + threadIdx.x;
  size_t stride = (size_t)gridDim.x * blockDim.x;
  const size_t n4 = (size_t)T_STEPS * 64 * IN_DIM / 4;
  const floatx4* xv = (const floatx4*)x;
  for (size_t idx = i; idx < n4; idx += stride) {
    floatx4 v = xv[idx];
    half4 h;
    h.x = (_Float16)v.x; h.y = (_Float16)v.y;
    h.z = (_Float16)v.z; h.w = (_Float16)v.w;
    *(half4*)(x16 + idx * 4) = h;
  }
  if (i < 16384) {
    // h0[-1] -> ring slot 7; h1[-1] -> parity 1 (LLC-coherent stores).
    cstore_pair(h0b + (size_t)(RING - 1) * 32768 + 2 * i, hc[2 * i], hc[2 * i + 1]);
    cstore_pair(h1b + 32768 + 2 * i, hc[32768 + 2 * i], hc[32768 + 2 * i + 1]);
  }
  if (i < 4096) {  // zero both flag arrays (2 x 8192 B contiguous)
    __hip_atomic_store(flagbase + i, 0u, __ATOMIC_RELAXED, __HIP_MEMORY_SCOPE_AGENT);
  }
}

// R8: R4's proven skeleton + load path (2x ld8 per phase, wait placement
// untouched). New: (1) register-resident gate phase via shfl_xor (no cbuf, no
// cstate LDS, both gate-phase syncthreads removed; c lives in 2 regs/lane);
// (2) per-wave sub-flags -> no release barrier (each wave's read-rows == its
// own written rows, so intra-block hazards don't exist); (3) L1's exposed top
// flags0 wait is skipped when the mid-step dual-poll already saw flags0>=t+2.
__global__ __launch_bounds__(256, 1) void lstm_kernel(
    const _Float16* __restrict__ x16, _Float16* __restrict__ h0b, _Float16* __restrict__ h1b,
    unsigned* __restrict__ flags0, unsigned* __restrict__ flags1,
    const float* __restrict__ W_ih0, const float* __restrict__ W_hh0,
    const float* __restrict__ b_ih0, const float* __restrict__ b_hh0,
    const float* __restrict__ W_ih1, const float* __restrict__ W_hh1,
    const float* __restrict__ b_ih1, const float* __restrict__ b_hh1,
    const float* __restrict__ W_out, const float* __restrict__ b_out,
    const float* __restrict__ hc, float* __restrict__ out) {
  __shared__ __align__(16) _Float16 wlds[32 * 1032];

  const int bq = blockIdx.x;
  const bool isL0 = bq < 64;
  const int q = isL0 ? bq : bq - 64;
  const int col0 = q * 8;
  const int Ka = isL0 ? IN_DIM : HID;
  const int K = Ka + HID;
  const int WP = K + 8;
  const int layer = isL0 ? 0 : 1;
  const float* Wa = isL0 ? W_ih0 : W_ih1;
  const float* Wb = isL0 ? W_hh0 : W_hh1;
  const float* bia = isL0 ? b_ih0 : b_ih1;
  const float* bib = isL0 ? b_hh0 : b_hh1;
  unsigned* myflag = (isL0 ? flags0 : flags1) + q * 32;

  for (int idx = threadIdx.x; idx < 32 * K; idx += 256) {
    int r = idx / K;
    int k = idx - r * K;
    int g = r >> 3, j = r & 7;
    int grow = g * HID + col0 + j;  // PyTorch gate order i,f,g,o
    float w = (k < Ka) ? Wa[(size_t)grow * Ka + k] : Wb[(size_t)grow * HID + (k - Ka)];
    wlds[r * WP + k] = (_Float16)w;
  }
  __syncthreads();

  const int lane = threadIdx.x & 63;
  const int wv = threadIdx.x >> 6;   // 0..3
  const int lrow = lane & 15;
  const int kq = (lane >> 4) * 8;
  const int m0 = wv * 16;
  const _Float16* wrow0 = wlds + lrow * WP;
  const _Float16* wrow1 = wlds + (16 + lrow) * WP;

  // Recurrent-half B fragments in registers/AGPRs (proven in R2/R3).
  half8 breg0[16], breg1[16];
#pragma unroll
  for (int c = 0; c < 16; ++c) {
    breg0[c] = *(const half8*)(wrow0 + Ka + c * 32 + kq);
    breg1[c] = *(const half8*)(wrow1 + Ka + c * 32 + kq);
  }

  // ---- register-gate-phase per-lane constants ----
  // acc reg r holds batch row m0+4*(lane>>4)+r, gate col lrow (acc0: i/f,
  // acc1: g/o). Lane pair (lane^8) swaps the i/g <-> f/o halves for the SAME
  // rows/col-j, so 4 shfl_xor(8) deliver the full gate set per lane.
  const int bsel = lrow >> 3;              // 0: owns i,g; 1: owns f,o
  const int jc = lrow & 7;                 // column within block's 8
  const int rbase = m0 + ((lane >> 4) << 2) + 2 * bsel;  // first of 2 rows
  const int colg = col0 + jc;
  const float bi_ = bia[colg] + bib[colg];
  const float bf_ = bia[HID + colg] + bib[HID + colg];
  const float bg_ = bia[2 * HID + colg] + bib[2 * HID + colg];
  const float bo_ = bia[3 * HID + colg] + bib[3 * HID + colg];
  float cst0 = hc[(size_t)(2 + layer) * 32768 + (size_t)(rbase + 0) * HID + colg];
  float cst1 = hc[(size_t)(2 + layer) * 32768 + (size_t)(rbase + 1) * HID + colg];

  bool skip0 = false;  // L1: mid-step dual-poll saw flags0 >= t+2

  for (int t = 0; t < T_STEPS; ++t) {
    floatx4 acc0 = {0.f, 0.f, 0.f, 0.f};
    floatx4 acc1 = {0.f, 0.f, 0.f, 0.f};
    _Float16* dst;
    half8 av[8];

    if (isL0) {
      // X phase (no cross-block dep): compute before the wait.
      const _Float16* a0p = x16 + (size_t)t * (64 * IN_DIM) + (m0 + lrow) * IN_DIM + kq;
#pragma unroll
      for (int c = 0; c < 8; ++c) {
        half8 a = *(const half8*)(a0p + c * 32);
        half8 b0v = *(const half8*)(wrow0 + c * 32 + kq);
        half8 b1v = *(const half8*)(wrow1 + c * 32 + kq);
        acc0 = mfma16(a, b0v, acc0);
        acc1 = mfma16(a, b1v, acc1);
      }
      // Merged wait: wave0 -> peers' h0[t-1]; wave1 -> ring slot free.
      if (threadIdx.x < 64) waitf4(flags0, (unsigned)t);
      else if (threadIdx.x < 128) waitf4(flags1, (t >= RING) ? (unsigned)(t - RING + 1) : 0u);
      __syncthreads();
      asm volatile("" ::: "memory");
      const _Float16* a1p = h0b + (size_t)((t - 1) & (RING - 1)) * 32768 + (m0 + lrow) * HID + kq;
      ld8_llc(a1p, av);
#pragma unroll
      for (int c = 0; c < 8; ++c) {
        acc0 = mfma16(av[c], breg0[c], acc0);
        acc1 = mfma16(av[c], breg1[c], acc1);
      }
      ld8_llc(a1p + 256, av);
#pragma unroll
      for (int c = 0; c < 8; ++c) {
        acc0 = mfma16(av[c], breg0[8 + c], acc0);
        acc1 = mfma16(av[c], breg1[8 + c], acc1);
      }
      dst = h0b + (size_t)(t & (RING - 1)) * 32768;
    } else {
      if (threadIdx.x < 64 && !skip0) waitf4(flags0, (unsigned)(t + 1));  // h0[t] ready
      __syncthreads();
      asm volatile("" ::: "memory");
      const _Float16* a0p = h0b + (size_t)(t & (RING - 1)) * 32768 + (m0 + lrow) * HID + kq;
      ld8_llc(a0p, av);
#pragma unroll
      for (int c = 0; c < 8; ++c) {
        half8 b0v = *(const half8*)(wrow0 + c * 32 + kq);
        half8 b1v = *(const half8*)(wrow1 + c * 32 + kq);
        acc0 = mfma16(av[c], b0v, acc0);
        acc1 = mfma16(av[c], b1v, acc1);
      }
      ld8_llc(a0p + 256, av);
#pragma unroll
      for (int c = 0; c < 8; ++c) {
        half8 b0v = *(const half8*)(wrow0 + (8 + c) * 32 + kq);
        half8 b1v = *(const half8*)(wrow1 + (8 + c) * 32 + kq);
        acc0 = mfma16(av[c], b0v, acc0);
        acc1 = mfma16(av[c], b1v, acc1);
      }
      // flags1 wait AFTER h0 phase (R4-proven placement); same round also
      // samples flags0>=t+2 so next step's top wait can be skipped for free.
      if (threadIdx.x < 64)
        skip0 = waitf4_dual(flags1, (unsigned)t, flags0, (unsigned)(t + 2));
      __syncthreads();
      asm volatile("" ::: "memory");
      const _Float16* a1p = h1b + (size_t)((t - 1) & 1) * 32768 + (m0 + lrow) * HID + kq;
      ld8_llc(a1p, av);
#pragma unroll
      for (int c = 0; c < 8; ++c) {
        acc0 = mfma16(av[c], breg0[c], acc0);
        acc1 = mfma16(av[c], breg1[c], acc1);
      }
      ld8_llc(a1p + 256, av);
#pragma unroll
      for (int c = 0; c < 8; ++c) {
        acc0 = mfma16(av[c], breg0[8 + c], acc0);
        acc1 = mfma16(av[c], breg1[8 + c], acc1);
      }
      dst = h1b + (size_t)(t & 1) * 32768;
    }

    // ---- register gate phase (no LDS, no barriers) ----
    // Exchange with lane^8: send the acc regs the peer's rows need, receive
    // ours. bsel=0 lane sends regs 2,3 / receives peer regs 0,1 (f,o for its
    // rows); bsel=1 symmetric.
    float s00 = __shfl_xor(bsel ? (float)acc0[0] : (float)acc0[2], 8);
    float s01 = __shfl_xor(bsel ? (float)acc0[1] : (float)acc0[3], 8);
    float s10 = __shfl_xor(bsel ? (float)acc1[0] : (float)acc1[2], 8);
    float s11 = __shfl_xor(bsel ? (float)acc1[1] : (float)acc1[3], 8);
    float hv0, hv1;
    {
      float o0 = bsel ? (float)acc0[2] : (float)acc0[0];
      float o1 = bsel ? (float)acc1[2] : (float)acc1[0];
      float gi = bsel ? s00 : o0;
      float gf = bsel ? o0 : s00;
      float gg = bsel ? s10 : o1;
      float go = bsel ? o1 : s10;
      float c = sig_f(gf + bf_) * cst0 + sig_f(gi + bi_) * tanh_f(gg + bg_);
      cst0 = c;
      hv0 = sig_f(go + bo_) * tanh_f(c);
    }
    {
      float o0 = bsel ? (float)acc0[3] : (float)acc0[1];
      float o1 = bsel ? (float)acc1[3] : (float)acc1[1];
      float gi = bsel ? s01 : o0;
      float gf = bsel ? o0 : s01;
      float gg = bsel ? s11 : o1;
      float go = bsel ? o1 : s11;
      float c = sig_f(gf + bf_) * cst1 + sig_f(gi + bi_) * tanh_f(gg + bg_);
      cst1 = c;
      hv1 = sig_f(go + bo_) * tanh_f(c);
    }
    // Pack adjacent columns (lane^1) so even-j lanes store 4B pairs.
    float hx0 = __shfl_xor(hv0, 1);
    float hx1 = __shfl_xor(hv1, 1);
    if ((jc & 1) == 0) {
      cstore_pair(dst + (size_t)(rbase + 0) * HID + col0 + jc, hv0, hx0);
      cstore_pair(dst + (size_t)(rbase + 1) * HID + col0 + jc, hv1, hx1);
    }

    // Release: per-wave drain + per-wave sub-flag; NO block barrier (each
    // wave's future reads touch only rows it wrote itself).
    asm volatile("s_waitcnt vmcnt(0)" ::: "memory");
    if ((threadIdx.x & 63) == 0) {
      __hip_atomic_store(myflag + wv, (unsigned)(t + 1), __ATOMIC_RELAXED,
                         __HIP_MEMORY_SCOPE_AGENT);
    }
    asm volatile("" ::: "memory");
  }

  // Final linear on L0 blocks: out[64,256] = h1[511] @ W_out^T + b_out.
  if (isL0) {
    if (threadIdx.x < 64) waitf4(flags1, (unsigned)T_STEPS);
    __syncthreads();
    asm volatile("" ::: "memory");
    const int oc = q * 4 + (threadIdx.x & 3);
    const int m = threadIdx.x >> 2;
    const _Float16* hrow = h1b + 32768 + m * HID;  // h1[511] at parity 1
    const float* wrow = W_out + (size_t)oc * HID;
    float sum = 0.f;
#pragma unroll 4
    for (int h = 0; h < HID; h += 8) {
      half8 hvv = cload_h8(hrow + h);
#pragma unroll
      for (int e = 0; e < 8; ++e) sum += (float)hvv[e] * wrow[h + e];
    }
    out[m * 256 + oc] = sum + b_out[oc];
  }
}

extern "C" void kernel_launch(void* const* d_in, const int* in_sizes, int n_in,
                              void* d_out, int out_size, void* d_ws, size_t ws_size,
                              hipStream_t stream) {
  const float* x     = (const float*)d_in[0];
  const float* hc    = (const float*)d_in[1];
  const float* W_ih0 = (const float*)d_in[2];
  const float* W_hh0 = (const float*)d_in[3];
  const float* b_ih0 = (const float*)d_in[4];
  const float* b_hh0 = (const float*)d_in[5];
  const float* W_ih1 = (const float*)d_in[6];
  const float* W_hh1 = (const float*)d_in[7];
  const float* b_ih1 = (const float*)d_in[8];
  const float* b_hh1 = (const float*)d_in[9];
  const float* W_out = (const float*)d_in[10];
  const float* b_out = (const float*)d_in[11];
  float* out = (float*)d_out;

  char* ws = (char*)d_ws;
  _Float16* x16 = (_Float16*)ws;                              // 16 MB
  _Float16* h0b = (_Float16*)(ws + 16777216);                 // 8 x 64 KB ring
  _Float16* h1b = (_Float16*)(ws + 16777216 + 8 * 65536);     // 2 x 64 KB
  unsigned* flags0 = (unsigned*)(ws + 16777216 + 10 * 65536);           // 64 x 128 B
  unsigned* flags1 = (unsigned*)(ws + 16777216 + 10 * 65536 + 8192);    // 64 x 128 B

  init_kernel<<<2048, 256, 0, stream>>>(x, hc, x16, h0b, h1b, flags0);
  lstm_kernel<<<128, 256, 0, stream>>>(x16, h0b, h1b, flags0, flags1,
                                       W_ih0, W_hh0, b_ih0, b_hh0,
                                       W_ih1, W_hh1, b_ih1, b_hh1,
                                       W_out, b_out, hc, out);
}